// Round 12
// baseline (43.090 us; speedup 1.0000x reference)
//
#include <hip/hip_runtime.h>
#include <math.h>

// zc layout: [(j2*16 + kko)][3072 rows][32 w] bf16, chunk-swizzled: logical 8-elem
//   chunk g of row r stored at chunk (g ^ ((r>>1)&3)). Plane = 98304 elems.
// dw layout: [kko(16)][512 k][32 w] bf16, same swizzle keyed on k.
#define ZSLAB 98304
#define DSLAB 16384

typedef __attribute__((ext_vector_type(8))) __bf16 bf16x8;
typedef __attribute__((ext_vector_type(4))) float  f32x4;

__device__ __forceinline__ unsigned short f2bf(float f) {
  union { float f; unsigned u; } v; v.f = f;
  unsigned r = v.u + 0x7fffu + ((v.u >> 16) & 1u);   // RNE
  return (unsigned short)(r >> 16);
}
__device__ __forceinline__ float bf2f_lo(unsigned u) {
  union { unsigned u; float f; } v; v.u = u << 16; return v.f;
}
__device__ __forceinline__ float bf2f_hi(unsigned u) {
  union { unsigned u; float f; } v; v.u = u & 0xffff0000u; return v.f;
}

__device__ const float DBC[8][8] = {
  { 0.35355339f,  0.35355339f,  0.35355339f,  0.35355339f,  0.35355339f,  0.35355339f,  0.35355339f,  0.35355339f},
  { 0.49039264f,  0.41573481f,  0.27778512f,  0.09754516f, -0.09754516f, -0.27778512f, -0.41573481f, -0.49039264f},
  { 0.46193977f,  0.19134172f, -0.19134172f, -0.46193977f, -0.46193977f, -0.19134172f,  0.19134172f,  0.46193977f},
  { 0.41573481f, -0.09754516f, -0.49039264f, -0.27778512f,  0.27778512f,  0.49039264f,  0.09754516f, -0.41573481f},
  { 0.35355339f, -0.35355339f, -0.35355339f,  0.35355339f,  0.35355339f, -0.35355339f, -0.35355339f,  0.35355339f},
  { 0.27778512f, -0.49039264f,  0.09754516f,  0.41573481f, -0.41573481f, -0.09754516f,  0.49039264f, -0.27778512f},
  { 0.19134172f, -0.46193977f,  0.46193977f, -0.19134172f, -0.19134172f,  0.46193977f, -0.46193977f,  0.19134172f},
  { 0.09754516f, -0.27778512f,  0.41573481f, -0.49039264f,  0.49039264f, -0.41573481f,  0.27778512f, -0.09754516f}
};

// ---------------- 1) pack + dw build fused. grid (512, 2) x 256 threads. (unchanged)
__global__ __launch_bounds__(256) void pack_all(const float* __restrict__ x,
                                                unsigned short* __restrict__ zc,
                                                unsigned short* __restrict__ dwf) {
  const int h = blockIdx.x, t = threadIdx.x;

  {
    const int idx = (blockIdx.y * 512 + blockIdx.x) * 256 + t;
    const int k = idx >> 9, w = idx & 511;
    const int n = (k * (2 * w + 1)) & 2047;                     // exact angle reduction
    const float c = __cosf((float)n * 0.0030679615757712823f);  // pi/1024
    const float scale = (k == 0) ? 0.04419417382415922f : 0.0625f;
    const int kko = w >> 5, g = (w >> 3) & 3, e = w & 7, s = (k >> 1) & 3;
    dwf[(size_t)kko * DSLAB + k * 32 + ((g ^ s) << 3) + e] = f2bf(c * scale);
  }

  const int c0 = blockIdx.y * 2048 + t * 8;   // this thread's 8 cols = one w, all j
  const float* xb = x + (size_t)(h * 8) * 4096 + c0;
  float q[8][8];
#pragma unroll
  for (int i = 0; i < 8; ++i) {
    float4 a = *reinterpret_cast<const float4*>(xb + (size_t)i * 4096);
    float4 b = *reinterpret_cast<const float4*>(xb + (size_t)i * 4096 + 4);
    q[i][0] = floorf(a.x * 255.0f); q[i][1] = floorf(a.y * 255.0f);
    q[i][2] = floorf(a.z * 255.0f); q[i][3] = floorf(a.w * 255.0f);
    q[i][4] = floorf(b.x * 255.0f); q[i][5] = floorf(b.y * 255.0f);
    q[i][6] = floorf(b.z * 255.0f); q[i][7] = floorf(b.w * 255.0f);
  }
  const int w0 = c0 >> 3;
  const int kko = w0 >> 5, g = (w0 >> 3) & 3, e = w0 & 7;
#pragma unroll
  for (int m = 2; m < 8; ++m) {
    const int row = h * 6 + (m - 2);
    const int s = (row >> 1) & 3;
    const size_t base = (size_t)row * 32 + ((g ^ s) << 3) + e;
#pragma unroll
    for (int j = 2; j < 8; ++j) {
      float v = 0.0f;
#pragma unroll
      for (int i = 0; i < 8; ++i) v = fmaf(DBC[m][i], q[i][j], v);
      zc[(size_t)((j - 2) * 16 + kko) * ZSLAB + base] = f2bf(v);
    }
  }
}

// ---------------- 2) fused batched-GEMM + interleave, 768 threads, 3-deep pipeline,
// ONE barrier per stage. Block (mt 0..63, nt 0..7).
// 12 waves; wave wv = (j2 = wv>>1, nhalf = wv&1): M=48 (3 frags), N=32 (2 frags),
// K=512, BK=32. Per-stage buffer = A 18432 B + B 4096 B = 22528 B; 3 buffers.
// Body t: [ds_reads(buf t%3); MFMA; WAITV(stage t+1 landed); s_barrier; STAGE(t+3)].
//   - data-ready: own vmcnt BEFORE shared barrier => all waves' stage-t+1 in LDS (m201).
//   - overwrite-safe: STAGE(t+3) -> buf t%3, which all waves finished reading (barrier).
//   - 2-stage DMA lookahead preserved; barriers 32 -> 17 per block.
#define OB_PITCH 392   // [row48][k*6 + j2]: write lanes stride 3 words (conflict-free)
__device__ __forceinline__ void gload16(const unsigned short* g, unsigned short* l) {
  __builtin_amdgcn_global_load_lds(
      (__attribute__((address_space(1))) void*)(g),
      (__attribute__((address_space(3))) void*)(l),
      16, 0, 0);
}

__global__ __launch_bounds__(768, 6) void fused_dct(const unsigned short* __restrict__ zc,
                                                    const unsigned short* __restrict__ dwf,
                                                    float* __restrict__ out) {
  const int bid = blockIdx.x;     // bid = nt*64+mt -> XCD = mt%8: same-mt blocks share L2
  const int mt  = bid & 63;
  const int nt  = bid >> 6;

  // LDS = 3 x 22528 = 67584 B -> 2 blocks/CU. Obuf (48*392*2 = 37632 B) aliases SM.
  __shared__ __align__(16) unsigned char SM[67584];
  unsigned short* SMu = (unsigned short*)SM;
  unsigned short* Obuf = (unsigned short*)SM;

  const int tid  = threadIdx.x;
  const int lane = tid & 63;
  const int wv   = tid >> 6;        // 0..11
  const int j2   = wv >> 1;         // 0..5 = j-2
  const int nh   = wv & 1;          // N-half (32 k)
  const int l15  = lane & 15;
  const int hi   = lane >> 4;

  // per-thread staging: exactly 2 gload16/stage; chunks f0=tid, f1=576+tid (A) keep
  // each issue lane-contiguous (dest = uniform base + lane*16B, m104 rule).
  const unsigned short *s0, *s1;
  int d0, d1;
  size_t step;
  if (tid < 576) {
    const int f0 = tid, f1 = 576 + tid;
    s0 = zc + (size_t)(f0 / 192) * 16 * ZSLAB + mt * 1536 + (f0 % 192) * 8;
    s1 = zc + (size_t)(f1 / 192) * 16 * ZSLAB + mt * 1536 + (f1 % 192) * 8;
    d0 = f0 * 8; d1 = f1 * 8;
    step = ZSLAB;
  } else {
    const int g0 = tid - 576, g1 = (192 + tid - 576) & 255;
    s0 = dwf + nt * 2048 + g0 * 8;
    s1 = dwf + nt * 2048 + g1 * 8;
    d0 = 9216 + g0 * 8; d1 = 9216 + g1 * 8;
    step = DSLAB;
  }

#define STAGE(buf, kko)                                                   \
  do {                                                                    \
    gload16(s0 + (size_t)(kko) * step, SMu + (buf) * 11264 + d0);         \
    gload16(s1 + (size_t)(kko) * step, SMu + (buf) * 11264 + d1);         \
  } while (0)

#define WAITV(n)                                                          \
  do {                                                                    \
    asm volatile("s_waitcnt vmcnt(" #n ")" ::: "memory");                 \
    __builtin_amdgcn_sched_barrier(0);                                    \
  } while (0)

  int aoff[3], boff[2];
#pragma unroll
  for (int mf = 0; mf < 3; ++mf) {
    const int r_ = mf * 16 + l15;
    aoff[mf] = j2 * 1536 + r_ * 32 + ((hi ^ ((r_ >> 1) & 3)) << 3);
  }
#pragma unroll
  for (int nf = 0; nf < 2; ++nf) {
    const int r_ = nh * 32 + nf * 16 + l15;
    boff[nf] = 9216 + r_ * 32 + ((hi ^ ((r_ >> 1) & 3)) << 3);
  }

  f32x4 acc[3][2] = {};

  // prologue: 3 stages in flight; wait stage 0, publish.
  STAGE(0, 0); STAGE(1, 1); STAGE(2, 2);
  WAITV(4);
  __builtin_amdgcn_s_barrier();

#pragma unroll
  for (int t = 0; t < 16; ++t) {
    {
      const unsigned short* Bb = SMu + (t % 3) * 11264;
      bf16x8 bfr[2], afr[3];
#pragma unroll
      for (int nf = 0; nf < 2; ++nf)
        bfr[nf] = *reinterpret_cast<const bf16x8*>(Bb + boff[nf]);
#pragma unroll
      for (int mf = 0; mf < 3; ++mf)
        afr[mf] = *reinterpret_cast<const bf16x8*>(Bb + aoff[mf]);
      __builtin_amdgcn_s_setprio(1);       // T5: pure-MFMA cluster
#pragma unroll
      for (int mf = 0; mf < 3; ++mf) {
        acc[mf][0] = __builtin_amdgcn_mfma_f32_16x16x32_bf16(afr[mf], bfr[0], acc[mf][0], 0, 0, 0);
        acc[mf][1] = __builtin_amdgcn_mfma_f32_16x16x32_bf16(afr[mf], bfr[1], acc[mf][1], 0, 0, 0);
      }
      __builtin_amdgcn_s_setprio(0);
    }
    if (t <= 13) {
      WAITV(2);                            // stage t+1 landed (t+2 may be in flight)
      __builtin_amdgcn_s_barrier();        // publish t+1; all done reading buf t%3
      STAGE(t % 3, t + 3);                 // refill just-freed buffer with stage t+3
    } else if (t == 14) {
      WAITV(0);                            // only stage 15 outstanding
      __builtin_amdgcn_s_barrier();
    }                                      // t == 15: nothing to wait for
  }
#undef STAGE
#undef WAITV

  __syncthreads();                // close loop epoch; Obuf may alias all buffers

  // ---- C -> Obuf: [row48][k*6 + j2], pitch 392
#pragma unroll
  for (int mf = 0; mf < 3; ++mf)
#pragma unroll
    for (int nf = 0; nf < 2; ++nf)
#pragma unroll
      for (int p = 0; p < 4; ++p)
        Obuf[(mf * 16 + hi * 4 + p) * OB_PITCH + (nh * 32 + nf * 16 + l15) * 6 + j2] =
            f2bf(acc[mf][nf][p]);
  __syncthreads();

  // ---- epilogue: 64 rows x 512 f32 cols; per f32x4 exactly two uniform b32 LDS reads
  float* outb = out + (size_t)(mt * 64) * 4096 + nt * 512;
  for (int v = tid; v < 8192; v += 768) {
    const int row64 = v >> 7;
    const int c4 = (v & 127) << 2;
    f32x4 val = {0.0f, 0.0f, 0.0f, 0.0f};
    const int m = row64 & 7;
    if (m >= 2) {
      const int row48 = (row64 >> 3) * 6 + (m - 2);
      const int kk = c4 >> 3, jb = c4 & 4;               // jb=0 -> j 0..3; jb=4 -> j 4..7
      const unsigned short* Ob = Obuf + row48 * OB_PITCH + kk * 6;
      const unsigned ua = *(const unsigned*)(Ob + (jb >> 1));  // jb=0: j2{0,1}; jb=4: j2{2,3}
      const unsigned ub = *(const unsigned*)(Ob + 4);          //               j2{4,5}
      if (jb) {
        val[0] = bf2f_lo(ua); val[1] = bf2f_hi(ua);
        val[2] = bf2f_lo(ub); val[3] = bf2f_hi(ub);
      } else {
        val[2] = bf2f_lo(ua); val[3] = bf2f_hi(ua);
      }
    }
    *reinterpret_cast<f32x4*>(outb + (size_t)row64 * 4096 + c4) = val;
  }
}

extern "C" void kernel_launch(void* const* d_in, const int* in_sizes, int n_in,
                              void* d_out, int out_size, void* d_ws, size_t ws_size,
                              hipStream_t stream) {
  const float* x = (const float*)d_in[0];
  float* out = (float*)d_out;
  char* ws = (char*)d_ws;

  unsigned short* dwf = (unsigned short*)ws;             // 512 KB
  unsigned short* zc  = (unsigned short*)(ws + 524288);  // 18.87 MB

  pack_all<<<dim3(512, 2), 256, 0, stream>>>(x, zc, dwf);
  fused_dct<<<512, 768, 0, stream>>>(zc, dwf, out);
}

// Round 13
// 41.722 us; speedup vs baseline: 1.0328x; 1.0328x over previous
//
#include <hip/hip_runtime.h>
#include <math.h>

// zc layout: [(j2*16 + kko)][3072 rows][32 w] bf16, chunk-swizzled: logical 8-elem
//   chunk g of row r stored at chunk (g ^ ((r>>1)&3)). Plane = 98304 elems.
// dw layout: [kko(16)][512 k][32 w] bf16, same swizzle keyed on k.
#define ZSLAB 98304
#define DSLAB 16384
#define SBUF  13312    // stage buffer elems: A 9216 + B 4096 (26624 B)
#define OB_PITCH 392   // Obuf [row48][k*6+j2]

typedef __attribute__((ext_vector_type(8))) __bf16 bf16x8;
typedef __attribute__((ext_vector_type(4))) float  f32x4;

__device__ __forceinline__ unsigned short f2bf(float f) {
  union { float f; unsigned u; } v; v.f = f;
  unsigned r = v.u + 0x7fffu + ((v.u >> 16) & 1u);   // RNE
  return (unsigned short)(r >> 16);
}
__device__ __forceinline__ float bf2f_lo(unsigned u) {
  union { unsigned u; float f; } v; v.u = u << 16; return v.f;
}
__device__ __forceinline__ float bf2f_hi(unsigned u) {
  union { unsigned u; float f; } v; v.u = u & 0xffff0000u; return v.f;
}

__device__ const float DBC[8][8] = {
  { 0.35355339f,  0.35355339f,  0.35355339f,  0.35355339f,  0.35355339f,  0.35355339f,  0.35355339f,  0.35355339f},
  { 0.49039264f,  0.41573481f,  0.27778512f,  0.09754516f, -0.09754516f, -0.27778512f, -0.41573481f, -0.49039264f},
  { 0.46193977f,  0.19134172f, -0.19134172f, -0.46193977f, -0.46193977f, -0.19134172f,  0.19134172f,  0.46193977f},
  { 0.41573481f, -0.09754516f, -0.49039264f, -0.27778512f,  0.27778512f,  0.49039264f,  0.09754516f, -0.41573481f},
  { 0.35355339f, -0.35355339f, -0.35355339f,  0.35355339f,  0.35355339f, -0.35355339f, -0.35355339f,  0.35355339f},
  { 0.27778512f, -0.49039264f,  0.09754516f,  0.41573481f, -0.41573481f, -0.09754516f,  0.49039264f, -0.27778512f},
  { 0.19134172f, -0.46193977f,  0.46193977f, -0.19134172f, -0.19134172f,  0.46193977f, -0.46193977f,  0.19134172f},
  { 0.09754516f, -0.27778512f,  0.41573481f, -0.49039264f,  0.49039264f, -0.41573481f,  0.27778512f, -0.09754516f}
};

// ---------------- 1) pack + dw build fused. grid (512, 2) x 256 threads. (unchanged)
__global__ __launch_bounds__(256) void pack_all(const float* __restrict__ x,
                                                unsigned short* __restrict__ zc,
                                                unsigned short* __restrict__ dwf) {
  const int h = blockIdx.x, t = threadIdx.x;

  {
    const int idx = (blockIdx.y * 512 + blockIdx.x) * 256 + t;
    const int k = idx >> 9, w = idx & 511;
    const int n = (k * (2 * w + 1)) & 2047;                     // exact angle reduction
    const float c = __cosf((float)n * 0.0030679615757712823f);  // pi/1024
    const float scale = (k == 0) ? 0.04419417382415922f : 0.0625f;
    const int kko = w >> 5, g = (w >> 3) & 3, e = w & 7, s = (k >> 1) & 3;
    dwf[(size_t)kko * DSLAB + k * 32 + ((g ^ s) << 3) + e] = f2bf(c * scale);
  }

  const int c0 = blockIdx.y * 2048 + t * 8;   // this thread's 8 cols = one w, all j
  const float* xb = x + (size_t)(h * 8) * 4096 + c0;
  float q[8][8];
#pragma unroll
  for (int i = 0; i < 8; ++i) {
    float4 a = *reinterpret_cast<const float4*>(xb + (size_t)i * 4096);
    float4 b = *reinterpret_cast<const float4*>(xb + (size_t)i * 4096 + 4);
    q[i][0] = floorf(a.x * 255.0f); q[i][1] = floorf(a.y * 255.0f);
    q[i][2] = floorf(a.z * 255.0f); q[i][3] = floorf(a.w * 255.0f);
    q[i][4] = floorf(b.x * 255.0f); q[i][5] = floorf(b.y * 255.0f);
    q[i][6] = floorf(b.z * 255.0f); q[i][7] = floorf(b.w * 255.0f);
  }
  const int w0 = c0 >> 3;
  const int kko = w0 >> 5, g = (w0 >> 3) & 3, e = w0 & 7;
#pragma unroll
  for (int m = 2; m < 8; ++m) {
    const int row = h * 6 + (m - 2);
    const int s = (row >> 1) & 3;
    const size_t base = (size_t)row * 32 + ((g ^ s) << 3) + e;
#pragma unroll
    for (int j = 2; j < 8; ++j) {
      float v = 0.0f;
#pragma unroll
      for (int i = 0; i < 8; ++i) v = fmaf(DBC[m][i], q[i][j], v);
      zc[(size_t)((j - 2) * 16 + kko) * ZSLAB + base] = f2bf(v);
    }
  }
}

// ---------------- 2) fused paired-tile GEMM + interleave. grid 256 (1 block/CU).
// Block (mt 0..63, np 0..3): out rows [mt*64,+64), cols [np*1024,+1024) (tiles tt=0,1).
// 12 waves (j2, nh). Per stage: A 18432B (shared by both tiles) + B 2x4096B; 4-deep.
// Staging rates: waves 0-8: 2 gload16/stage; waves 9-10: 4; wave 11: 0 (writes the
// mask-zero output rows during the loop instead - its vmcnt is never consulted).
__device__ __forceinline__ void gload16(const unsigned short* g, unsigned short* l) {
  __builtin_amdgcn_global_load_lds(
      (__attribute__((address_space(1))) void*)(g),
      (__attribute__((address_space(3))) void*)(l),
      16, 0, 0);
}

__global__ __launch_bounds__(768, 3) void fused_dct(const unsigned short* __restrict__ zc,
                                                    const unsigned short* __restrict__ dwf,
                                                    float* __restrict__ out) {
  const int bid = blockIdx.x;     // bid = np*64+mt -> XCD = mt%8: same-mt blocks share L2
  const int mt  = bid & 63;
  const int np  = bid >> 6;

  // LDS: 4 stage buffers x 26624B = 106496B. Obuf (37632B) aliases buffers 0..2
  // (final body reads buffer 3 at [79872,106496) - disjoint).
  __shared__ __align__(16) unsigned char SM[106496];
  unsigned short* SMu  = (unsigned short*)SM;
  unsigned short* Obuf = (unsigned short*)SM;

  const int tid  = threadIdx.x;
  const int lane = tid & 63;
  const int wv   = tid >> 6;        // 0..11
  const int j2   = wv >> 1;         // 0..5 = j-2
  const int nh   = wv & 1;          // N-half within a tile (32 k)
  const int l15  = lane & 15;
  const int hi   = lane >> 4;

  // staging sources/dests (m104: each issue = wave-uniform LDS base + lane*16B)
  const unsigned short *sA0, *sA1, *sB0, *sB1, *sB2, *sB3;
  int dA0, dA1, dB0, dB1, dB2, dB3;
  {
    const int f0 = tid, f1 = 576 + tid;              // A chunks (tid<576)
    sA0 = zc + (size_t)(f0 / 192) * 16 * ZSLAB + mt * 1536 + (f0 % 192) * 8;
    sA1 = zc + (size_t)(f1 / 192) * 16 * ZSLAB + mt * 1536 + (f1 % 192) * 8;
    dA0 = f0 * 8; dA1 = f1 * 8;
    const int bt = tid - 576;                        // B chunks (waves 9,10: bt 0..127)
    const int g0 = bt, g1 = 128 + bt, g2 = 256 + bt, g3 = 384 + bt;
    sB0 = dwf + (np * 2 + 0) * 2048 + (g0 & 255) * 8;
    sB1 = dwf + (np * 2 + 0) * 2048 + (g1 & 255) * 8;
    sB2 = dwf + (np * 2 + 1) * 2048 + (g2 & 255) * 8;
    sB3 = dwf + (np * 2 + 1) * 2048 + (g3 & 255) * 8;
    dB0 = 9216 + g0 * 8; dB1 = 9216 + g1 * 8; dB2 = 9216 + g2 * 8; dB3 = 9216 + g3 * 8;
  }

#define STAGE(buf, kko)                                                       \
  do {                                                                        \
    unsigned short* L_ = SMu + (buf) * SBUF;                                  \
    if (tid < 576) {                                                          \
      gload16(sA0 + (size_t)(kko) * ZSLAB, L_ + dA0);                         \
      gload16(sA1 + (size_t)(kko) * ZSLAB, L_ + dA1);                         \
    } else if (tid < 704) {                                                   \
      gload16(sB0 + (size_t)(kko) * DSLAB, L_ + dB0);                         \
      gload16(sB1 + (size_t)(kko) * DSLAB, L_ + dB1);                         \
      gload16(sB2 + (size_t)(kko) * DSLAB, L_ + dB2);                         \
      gload16(sB3 + (size_t)(kko) * DSLAB, L_ + dB3);                         \
    }                                                                         \
  } while (0)

  // wave-classed counted waits (+ zero-row stores for wave 11)
  float* const zbase = out + (size_t)(mt * 64) * 4096 + np * 1024;
#define WAITW(na, nb, t)                                                      \
  do {                                                                        \
    if (wv < 9) {                                                             \
      asm volatile("s_waitcnt vmcnt(" #na ")" ::: "memory");                  \
      __builtin_amdgcn_sched_barrier(0);                                      \
    } else if (wv < 11) {                                                     \
      asm volatile("s_waitcnt vmcnt(" #nb ")" ::: "memory");                  \
      __builtin_amdgcn_sched_barrier(0);                                      \
    } else {                                                                  \
      _Pragma("unroll")                                                       \
      for (int q_ = 0; q_ < 4; ++q_) {                                        \
        const int e_ = (t) * 4 + q_;                                          \
        const int r16_ = e_ >> 2;                                             \
        float* p_ = zbase + (size_t)((r16_ >> 1) * 8 + (r16_ & 1)) * 4096 +   \
                    (e_ & 3) * 256 + lane * 4;                                \
        *reinterpret_cast<f32x4*>(p_) = (f32x4){0.f, 0.f, 0.f, 0.f};          \
      }                                                                       \
    }                                                                         \
  } while (0)

  // read offsets (producer swizzle: chunk ^= (row>>1)&3; block bases mult. of 16)
  int aoff[3], boffA[2], boffB[2];
#pragma unroll
  for (int mf = 0; mf < 3; ++mf) {
    const int r_ = mf * 16 + l15;
    aoff[mf] = j2 * 1536 + r_ * 32 + ((hi ^ ((r_ >> 1) & 3)) << 3);
  }
#pragma unroll
  for (int nf = 0; nf < 2; ++nf) {
    const int r_ = nh * 32 + nf * 16 + l15;
    const int sw = r_ * 32 + ((hi ^ ((r_ >> 1) & 3)) << 3);
    boffA[nf] = 9216 + sw;
    boffB[nf] = 11264 + sw;
  }

  f32x4 accA[3][2] = {}, accB[3][2] = {};

  STAGE(0, 0); STAGE(1, 1); STAGE(2, 2); STAGE(3, 3);
#pragma unroll
  for (int t = 0; t < 16; ++t) {
    // allow 3 in-flight stages (tail shrinks)
    if (t <= 12)      WAITW(6, 12, t);
    else if (t == 13) WAITW(4, 8, t);
    else if (t == 14) WAITW(2, 4, t);
    else              WAITW(0, 0, t);
    __builtin_amdgcn_s_barrier();          // stage t visible to all waves
    {
      const unsigned short* Bb = SMu + (t & 3) * SBUF;
      bf16x8 afr[3], bfa[2], bfb[2];
#pragma unroll
      for (int mf = 0; mf < 3; ++mf)
        afr[mf] = *reinterpret_cast<const bf16x8*>(Bb + aoff[mf]);
#pragma unroll
      for (int nf = 0; nf < 2; ++nf) {
        bfa[nf] = *reinterpret_cast<const bf16x8*>(Bb + boffA[nf]);
        bfb[nf] = *reinterpret_cast<const bf16x8*>(Bb + boffB[nf]);
      }
      __builtin_amdgcn_s_setprio(1);       // T5: pure-MFMA cluster (12 MFMA)
#pragma unroll
      for (int mf = 0; mf < 3; ++mf) {
        accA[mf][0] = __builtin_amdgcn_mfma_f32_16x16x32_bf16(afr[mf], bfa[0], accA[mf][0], 0, 0, 0);
        accA[mf][1] = __builtin_amdgcn_mfma_f32_16x16x32_bf16(afr[mf], bfa[1], accA[mf][1], 0, 0, 0);
        accB[mf][0] = __builtin_amdgcn_mfma_f32_16x16x32_bf16(afr[mf], bfb[0], accB[mf][0], 0, 0, 0);
        accB[mf][1] = __builtin_amdgcn_mfma_f32_16x16x32_bf16(afr[mf], bfb[1], accB[mf][1], 0, 0, 0);
      }
      __builtin_amdgcn_s_setprio(0);
    }
    asm volatile("s_waitcnt lgkmcnt(0)" ::: "memory");  // own reads of buf t&3 done
    __builtin_amdgcn_s_barrier();                       // everyone's reads done
    if (t <= 11) STAGE(t & 3, t + 4);                   // refill with stage t+4
  }
#undef STAGE
#undef WAITW

  __syncthreads();                // close loop epoch; Obuf may alias buffers 0..2

  // ---- two tiles: acc -> Obuf -> coalesced stores (rows m>=2 only; zeros done)
#pragma unroll
  for (int tt = 0; tt < 2; ++tt) {
#pragma unroll
    for (int mf = 0; mf < 3; ++mf)
#pragma unroll
      for (int nf = 0; nf < 2; ++nf)
#pragma unroll
        for (int p = 0; p < 4; ++p) {
          const float vv = tt ? accB[mf][nf][p] : accA[mf][nf][p];
          Obuf[(mf * 16 + hi * 4 + p) * OB_PITCH + (nh * 32 + nf * 16 + l15) * 6 + j2] =
              f2bf(vv);
        }
    asm volatile("s_waitcnt lgkmcnt(0)" ::: "memory");
    __builtin_amdgcn_s_barrier();          // Obuf fully written

    float* outt = out + (size_t)(mt * 64) * 4096 + (np * 2 + tt) * 512;
    for (int v = tid; v < 6144; v += 768) {
      const int row48 = v >> 7;
      const int c4 = (v & 127) << 2;
      const int hg = row48 / 6, mm = row48 - hg * 6;
      const int row64 = hg * 8 + 2 + mm;
      const int kk = c4 >> 3, jb = c4 & 4;
      const unsigned short* Ob = Obuf + row48 * OB_PITCH + kk * 6;
      const unsigned ua = *(const unsigned*)(Ob + (jb >> 1));
      const unsigned ub = *(const unsigned*)(Ob + 4);
      f32x4 val;
      if (jb) {
        val[0] = bf2f_lo(ua); val[1] = bf2f_hi(ua);
        val[2] = bf2f_lo(ub); val[3] = bf2f_hi(ub);
      } else {
        val[0] = 0.f; val[1] = 0.f;
        val[2] = bf2f_lo(ua); val[3] = bf2f_hi(ua);
      }
      *reinterpret_cast<f32x4*>(outt + (size_t)row64 * 4096 + c4) = val;
    }
    if (tt == 0) {
      asm volatile("s_waitcnt lgkmcnt(0)" ::: "memory");  // Obuf reads done
      __builtin_amdgcn_s_barrier();                       // before overwrite
    }
  }
}

extern "C" void kernel_launch(void* const* d_in, const int* in_sizes, int n_in,
                              void* d_out, int out_size, void* d_ws, size_t ws_size,
                              hipStream_t stream) {
  const float* x = (const float*)d_in[0];
  float* out = (float*)d_out;
  char* ws = (char*)d_ws;

  unsigned short* dwf = (unsigned short*)ws;             // 512 KB
  unsigned short* zc  = (unsigned short*)(ws + 524288);  // 18.87 MB

  pack_all<<<dim3(512, 2), 256, 0, stream>>>(x, zc, dwf);
  fused_dct<<<256, 768, 0, stream>>>(zc, dwf, out);
}